// Round 3
// baseline (15959.145 us; speedup 1.0000x reference)
//
#include <hip/hip_runtime.h>

typedef unsigned short u16;
typedef float f32x4 __attribute__((ext_vector_type(4)));
typedef short s16x8 __attribute__((ext_vector_type(8)));
typedef unsigned short u16x4 __attribute__((ext_vector_type(4)));

static constexpr int NN = 100000;          // nodes
static constexpr int NP = 100096;          // padded to 782*128
static constexpr int EE = 1600000;         // edges
static constexpr int ET = EE + NN;         // edges + self loops
static constexpr long ZO = 4000000;        // offset of log_softmax in d_out

__device__ __forceinline__ u16 f2bf(float f) {
    unsigned u = __float_as_uint(f);
    return (u16)((u + 0x7FFFu + ((u >> 16) & 1u)) >> 16);
}
__device__ __forceinline__ float lrelu(float x) { return x > 0.f ? x : 0.2f * x; }
// order-preserving float<->uint encode for atomicMax
__device__ __forceinline__ unsigned fenc(float f) {
    unsigned u = __float_as_uint(f);
    return (u & 0x80000000u) ? ~u : (u | 0x80000000u);
}
__device__ __forceinline__ float fdec(unsigned u) {
    return (u & 0x80000000u) ? __uint_as_float(u ^ 0x80000000u) : __uint_as_float(~u);
}
__device__ __forceinline__ void edge_nodes(int idx, const int* __restrict__ ei, int& s, int& d) {
    if (idx < EE) { s = ei[idx]; d = ei[EE + idx]; } else { s = d = idx - EE; }
}

// ---- conversions ----
__global__ void k_conv_x(const float* __restrict__ x, u16* __restrict__ xb) {
    long i = (long)blockIdx.x * blockDim.x + threadIdx.x;   // float4 index
    if (i >= (long)NP * 64) return;
    long row = i >> 6;
    u16x4 o; o[0] = 0; o[1] = 0; o[2] = 0; o[3] = 0;
    if (row < NN) {
        f32x4 v = ((const f32x4*)x)[i];
        o[0] = f2bf(v[0]); o[1] = f2bf(v[1]); o[2] = f2bf(v[2]); o[3] = f2bf(v[3]);
    }
    ((u16x4*)xb)[i] = o;
}
__global__ void k_conv_w1t(const float* __restrict__ W1, u16* __restrict__ w1t) {
    int t = blockIdx.x * blockDim.x + threadIdx.x;  // [128 cols][256 k]
    if (t >= 128 * 256) return;
    int c = t >> 8, k = t & 255;
    w1t[t] = f2bf(W1[k * 128 + c]);
}
__global__ void k_conv_w2t(const float* __restrict__ W2, u16* __restrict__ w2t) {
    int t = blockIdx.x * blockDim.x + threadIdx.x;  // [48 cols][128 k], cols 40..47 zero
    if (t >= 48 * 128) return;
    int c = t >> 7, k = t & 127;
    w2t[t] = (c < 40) ? f2bf(W2[k * 40 + c]) : (u16)0;
}

// ---- GEMM1: H1[100k,128] = x @ W1 (bf16 MFMA, 128-row blocks, BK=128) ----
__global__ __launch_bounds__(256) void k_gemm1(const u16* __restrict__ xb,
                                               const u16* __restrict__ w1t,
                                               float* __restrict__ H1) {
    __shared__ u16 As[128 * 128];
    __shared__ u16 Bs[128 * 128];
    char* Ab = (char*)As; char* Bb = (char*)Bs;
    int t = threadIdx.x;
    int lane = t & 63, wv = t >> 6;
    int wr = wv >> 1, wc = wv & 1;          // wave quadrant
    int lr = lane & 15, lk = lane >> 4;
    long rb = (long)blockIdx.x * 128;
    f32x4 acc[4][4];
    for (int m = 0; m < 4; ++m) for (int n = 0; n < 4; ++n)
        { acc[m][n][0] = 0.f; acc[m][n][1] = 0.f; acc[m][n][2] = 0.f; acc[m][n][3] = 0.f; }
    for (int kh = 0; kh < 2; ++kh) {
        __syncthreads();
        for (int i = 0; i < 8; ++i) {       // 2048 16B chunks each for A and B
            int j = t + i * 256;
            int row = j >> 4, wi = j & 15;
            s16x8 va = *(const s16x8*)(xb + (rb + row) * 256 + kh * 128 + wi * 8);
            *(s16x8*)(Ab + row * 256 + ((wi * 16) ^ ((row & 7) << 4))) = va;
            s16x8 vb = *(const s16x8*)(w1t + row * 256 + kh * 128 + wi * 8); // row==col
            *(s16x8*)(Bb + row * 256 + ((wi * 16) ^ ((row & 7) << 4))) = vb;
        }
        __syncthreads();
        for (int ks = 0; ks < 4; ++ks) {
            s16x8 a[4], b[4];
            for (int m = 0; m < 4; ++m) {
                int r = wr * 64 + m * 16 + lr;
                a[m] = *(const s16x8*)(Ab + r * 256 + ((ks * 64 + lk * 16) ^ ((r & 7) << 4)));
            }
            for (int n = 0; n < 4; ++n) {
                int c = wc * 64 + n * 16 + lr;
                b[n] = *(const s16x8*)(Bb + c * 256 + ((ks * 64 + lk * 16) ^ ((c & 7) << 4)));
            }
            for (int m = 0; m < 4; ++m)
                for (int n = 0; n < 4; ++n)
                    acc[m][n] = __builtin_amdgcn_mfma_f32_16x16x32_bf16(a[m], b[n], acc[m][n], 0, 0, 0);
        }
    }
    for (int m = 0; m < 4; ++m)
        for (int n = 0; n < 4; ++n)
            for (int r = 0; r < 4; ++r) {
                long row = rb + wr * 64 + m * 16 + lk * 4 + r;
                int col = wc * 64 + n * 16 + lr;
                if (row < NN) H1[row * 128 + col] = acc[m][n][r];
            }
}

// ---- alpha1: per (node,head) dot of h with a_src/a_dst ----
__global__ void k_alpha1(const float* __restrict__ H1, const float* __restrict__ asw,
                         const float* __restrict__ adw, float* __restrict__ as1,
                         float* __restrict__ ad1) {
    int idx = blockIdx.x * blockDim.x + threadIdx.x;
    if (idx >= NN * 4) return;
    int n = idx >> 2, h = idx & 3;
    const f32x4* hp = (const f32x4*)(H1 + (long)n * 128 + h * 32);
    const f32x4* sp = (const f32x4*)(asw + h * 32);
    const f32x4* dp = (const f32x4*)(adw + h * 32);
    float s = 0.f, d = 0.f;
    for (int i = 0; i < 8; ++i) {
        f32x4 hv = hp[i], sv = sp[i], dv = dp[i];
        s += hv[0] * sv[0] + hv[1] * sv[1] + hv[2] * sv[2] + hv[3] * sv[3];
        d += hv[0] * dv[0] + hv[1] * dv[1] + hv[2] * dv[2] + hv[3] * dv[3];
    }
    as1[idx] = s; ad1[idx] = d;
}

// ---- layer-1 edge passes ----
__global__ void k_passA1(const int* __restrict__ ei, const float* __restrict__ as1,
                         const float* __restrict__ ad1, unsigned* __restrict__ max1) {
    int idx = blockIdx.x * blockDim.x + threadIdx.x;
    if (idx >= ET) return;
    int s, d; edge_nodes(idx, ei, s, d);
    f32x4 a = *(const f32x4*)(as1 + (long)s * 4);
    f32x4 b = *(const f32x4*)(ad1 + (long)d * 4);
    for (int h = 0; h < 4; ++h) {
        float e = lrelu(a[h] + b[h]);
        atomicMax(max1 + (long)d * 4 + h, fenc(e));
    }
}
__global__ void k_passB1(const int* __restrict__ ei, const float* __restrict__ as1,
                         const float* __restrict__ ad1, const unsigned* __restrict__ max1,
                         float* __restrict__ den1) {
    int idx = blockIdx.x * blockDim.x + threadIdx.x;
    if (idx >= ET) return;
    int s, d; edge_nodes(idx, ei, s, d);
    f32x4 a = *(const f32x4*)(as1 + (long)s * 4);
    f32x4 b = *(const f32x4*)(ad1 + (long)d * 4);
    for (int h = 0; h < 4; ++h) {
        float e = lrelu(a[h] + b[h]);
        float m = fdec(max1[(long)d * 4 + h]);
        atomicAdd(den1 + (long)d * 4 + h, expf(e - m));
    }
}
__global__ void k_passC1(const int* __restrict__ ei, const float* __restrict__ as1,
                         const float* __restrict__ ad1, const unsigned* __restrict__ max1,
                         const float* __restrict__ den1, const float* __restrict__ H1,
                         float* __restrict__ out1) {
    long tid = (long)blockIdx.x * blockDim.x + threadIdx.x;
    if (tid >= (long)ET * 4) return;
    int idx = (int)(tid >> 2), h = (int)(tid & 3);
    int s, d; edge_nodes(idx, ei, s, d);
    float e = lrelu(as1[(long)s * 4 + h] + ad1[(long)d * 4 + h]);
    float m = fdec(max1[(long)d * 4 + h]);
    float w = expf(e - m) / (den1[(long)d * 4 + h] + 1e-16f);
    const float* hr = H1 + (long)s * 128 + h * 32;
    float* orow = out1 + (long)d * 128 + h * 32;
    for (int i = 0; i < 8; ++i) {
        f32x4 v = *(const f32x4*)(hr + i * 4);
        atomicAdd(orow + i * 4 + 0, v[0] * w);
        atomicAdd(orow + i * 4 + 1, v[1] * w);
        atomicAdd(orow + i * 4 + 2, v[2] * w);
        atomicAdd(orow + i * 4 + 3, v[3] * w);
    }
}

// ---- activation: h1act_bf16 = lrelu(out1 + b1), padded rows zeroed ----
__global__ void k_act(const float* __restrict__ out1, const float* __restrict__ b1,
                      u16* __restrict__ h1b) {
    long tid = (long)blockIdx.x * blockDim.x + threadIdx.x;  // per 4 cols
    if (tid >= (long)NP * 32) return;
    long row = tid >> 5; int cg = (int)(tid & 31);
    u16x4 o; o[0] = 0; o[1] = 0; o[2] = 0; o[3] = 0;
    if (row < NN) {
        f32x4 v = *(const f32x4*)(out1 + row * 128 + cg * 4);
        f32x4 bb = *(const f32x4*)(b1 + cg * 4);
        for (int j = 0; j < 4; ++j) o[j] = f2bf(lrelu(v[j] + bb[j]));
    }
    ((u16x4*)h1b)[tid] = o;
}

// ---- GEMM2: H2[100k,40] = h1act @ W2 (bf16 MFMA, cols padded to 48) ----
__global__ __launch_bounds__(256) void k_gemm2(const u16* __restrict__ h1b,
                                               const u16* __restrict__ w2t,
                                               float* __restrict__ H2) {
    __shared__ u16 As[128 * 128];   // 32KB
    __shared__ u16 Bs[48 * 128];    // 12KB
    char* Ab = (char*)As; char* Bb = (char*)Bs;
    int t = threadIdx.x;
    int lane = t & 63, wv = t >> 6;      // wave owns 32 rows, all 48 cols
    int lr = lane & 15, lk = lane >> 4;
    long rb = (long)blockIdx.x * 128;
    f32x4 acc[2][3];
    for (int m = 0; m < 2; ++m) for (int n = 0; n < 3; ++n)
        { acc[m][n][0] = 0.f; acc[m][n][1] = 0.f; acc[m][n][2] = 0.f; acc[m][n][3] = 0.f; }
    for (int i = 0; i < 8; ++i) {
        int j = t + i * 256;
        int row = j >> 4, wi = j & 15;
        s16x8 va = *(const s16x8*)(h1b + (rb + row) * 128 + wi * 8);
        *(s16x8*)(Ab + row * 256 + ((wi * 16) ^ ((row & 7) << 4))) = va;
    }
    for (int i = 0; i < 3; ++i) {
        int j = t + i * 256;
        int col = j >> 4, wi = j & 15;
        s16x8 vb = *(const s16x8*)(w2t + col * 128 + wi * 8);
        *(s16x8*)(Bb + col * 256 + ((wi * 16) ^ ((col & 7) << 4))) = vb;
    }
    __syncthreads();
    for (int ks = 0; ks < 4; ++ks) {
        s16x8 a[2], b[3];
        for (int m = 0; m < 2; ++m) {
            int r = wv * 32 + m * 16 + lr;
            a[m] = *(const s16x8*)(Ab + r * 256 + ((ks * 64 + lk * 16) ^ ((r & 7) << 4)));
        }
        for (int n = 0; n < 3; ++n) {
            int c = n * 16 + lr;
            b[n] = *(const s16x8*)(Bb + c * 256 + ((ks * 64 + lk * 16) ^ ((c & 7) << 4)));
        }
        for (int m = 0; m < 2; ++m)
            for (int n = 0; n < 3; ++n)
                acc[m][n] = __builtin_amdgcn_mfma_f32_16x16x32_bf16(a[m], b[n], acc[m][n], 0, 0, 0);
    }
    for (int m = 0; m < 2; ++m)
        for (int n = 0; n < 3; ++n)
            for (int r = 0; r < 4; ++r) {
                long row = rb + wv * 32 + m * 16 + lk * 4 + r;
                int col = n * 16 + lr;
                if (row < NN && col < 40) H2[row * 40 + col] = acc[m][n][r];
            }
}

__global__ void k_alpha2(const float* __restrict__ H2, const float* __restrict__ asw,
                         const float* __restrict__ adw, float* __restrict__ as2,
                         float* __restrict__ ad2) {
    int n = blockIdx.x * blockDim.x + threadIdx.x;
    if (n >= NN) return;
    float s = 0.f, d = 0.f;
    for (int c = 0; c < 40; c += 4) {
        f32x4 h = *(const f32x4*)(H2 + (long)n * 40 + c);
        f32x4 sv = *(const f32x4*)(asw + c);
        f32x4 dv = *(const f32x4*)(adw + c);
        s += h[0] * sv[0] + h[1] * sv[1] + h[2] * sv[2] + h[3] * sv[3];
        d += h[0] * dv[0] + h[1] * dv[1] + h[2] * dv[2] + h[3] * dv[3];
    }
    as2[n] = s; ad2[n] = d;
}

// ---- layer-2 edge passes (H=1) ----
__global__ void k_passA2(const int* __restrict__ ei, const float* __restrict__ as2,
                         const float* __restrict__ ad2, unsigned* __restrict__ max2) {
    int idx = blockIdx.x * blockDim.x + threadIdx.x;
    if (idx >= ET) return;
    int s, d; edge_nodes(idx, ei, s, d);
    float e = lrelu(as2[s] + ad2[d]);
    atomicMax(max2 + d, fenc(e));
}
__global__ void k_passB2(const int* __restrict__ ei, const float* __restrict__ as2,
                         const float* __restrict__ ad2, const unsigned* __restrict__ max2,
                         float* __restrict__ den2) {
    int idx = blockIdx.x * blockDim.x + threadIdx.x;
    if (idx >= ET) return;
    int s, d; edge_nodes(idx, ei, s, d);
    float e = lrelu(as2[s] + ad2[d]);
    atomicAdd(den2 + d, expf(e - fdec(max2[d])));
}
__global__ void k_passC2(const int* __restrict__ ei, const float* __restrict__ as2,
                         const float* __restrict__ ad2, const unsigned* __restrict__ max2,
                         const float* __restrict__ den2, const float* __restrict__ H2,
                         float* __restrict__ zacc) {
    int idx = blockIdx.x * blockDim.x + threadIdx.x;
    if (idx >= ET) return;
    int s, d; edge_nodes(idx, ei, s, d);
    float e = lrelu(as2[s] + ad2[d]);
    float w = expf(e - fdec(max2[d])) / (den2[d] + 1e-16f);
    const float* hr = H2 + (long)s * 40;
    float* orow = zacc + (long)d * 40;
    for (int c = 0; c < 40; c += 4) {
        f32x4 v = *(const f32x4*)(hr + c);
        atomicAdd(orow + c + 0, v[0] * w);
        atomicAdd(orow + c + 1, v[1] * w);
        atomicAdd(orow + c + 2, v[2] * w);
        atomicAdd(orow + c + 3, v[3] * w);
    }
}

// ---- final: z += b2 (write), log_softmax (write). wave per node row ----
__global__ void k_final(float* __restrict__ out, const float* __restrict__ b2) {
    int wv = threadIdx.x >> 6, lane = threadIdx.x & 63;
    long n = (long)blockIdx.x * 4 + wv;
    if (n >= NN) return;
    float zv = 0.f, mv = -__builtin_inff();
    if (lane < 40) { zv = out[n * 40 + lane] + b2[lane]; mv = zv; }
    for (int s = 1; s < 64; s <<= 1) mv = fmaxf(mv, __shfl_xor(mv, s, 64));
    float ex = (lane < 40) ? expf(zv - mv) : 0.f;
    for (int s = 1; s < 64; s <<= 1) ex += __shfl_xor(ex, s, 64);
    if (lane < 40) {
        out[n * 40 + lane] = zv;
        out[ZO + n * 40 + lane] = zv - mv - logf(ex);
    }
}

extern "C" void kernel_launch(void* const* d_in, const int* in_sizes, int n_in,
                              void* d_out, int out_size, void* d_ws, size_t ws_size,
                              hipStream_t stream) {
    const float* x   = (const float*)d_in[0];
    const int*   ei  = (const int*)d_in[1];
    const float* W1  = (const float*)d_in[2];
    const float* aS1 = (const float*)d_in[3];
    const float* aD1 = (const float*)d_in[4];
    const float* b1  = (const float*)d_in[5];
    const float* W2  = (const float*)d_in[6];
    const float* aS2 = (const float*)d_in[7];
    const float* aD2 = (const float*)d_in[8];
    const float* b2  = (const float*)d_in[9];
    float* out = (float*)d_out;

    // workspace layout (126.5 MB, regions aliased across phases)
    char* p = (char*)d_ws;
    u16*      xb   = (u16*)p;                       // 51,249,152 bytes (NP*256*2)
    float*    out1 = (float*)p;                     // alias: after gemm1, 51.2MB
    float*    H1   = (float*)(p + 51249152);        // 51,200,000 bytes
    u16*      h1b  = (u16*)(p + 51249152);          // alias: after passC1, 25.6MB
    float*    H2   = (float*)(p + 102449152);       // 16,000,000 bytes
    u16*      w1t  = (u16*)(p + 118449152);         // 65,536 bytes
    u16*      w2t  = (u16*)(p + 118514688);         // 12,288 bytes
    float*    as1  = (float*)(p + 118526976);       // 1,600,000 bytes
    float*    ad1  = (float*)(p + 120126976);       // 1,600,000 bytes
    float*    as2  = (float*)(p + 121726976);       // 400,000 bytes
    float*    ad2  = (float*)(p + 122126976);       // 400,000 bytes
    unsigned* max1 = (unsigned*)(p + 122526976);    // 1,600,000 bytes (one memset covers
    float*    den1 = (float*)(p + 124126976);       // 1,600,000 bytes  max1/den1/max2/den2
    unsigned* max2 = (unsigned*)(p + 125726976);    // 400,000 bytes    = 4,000,000 total)
    float*    den2 = (float*)(p + 126126976);       // 400,000 bytes

    (void)hipMemsetAsync(max1, 0, 4000000, stream);        // max/den both layers
    (void)hipMemsetAsync(out, 0, (size_t)ZO * 4, stream);  // z accumulator

    k_conv_x  <<<25024, 256, 0, stream>>>(x, xb);
    k_conv_w1t<<<128, 256, 0, stream>>>(W1, w1t);
    k_conv_w2t<<<24, 256, 0, stream>>>(W2, w2t);
    k_gemm1   <<<782, 256, 0, stream>>>(xb, w1t, H1);
    k_alpha1  <<<1563, 256, 0, stream>>>(H1, aS1, aD1, as1, ad1);
    (void)hipMemsetAsync(out1, 0, (size_t)NN * 128 * 4, stream);  // after gemm1 (aliases xb)
    k_passA1  <<<6641, 256, 0, stream>>>(ei, as1, ad1, max1);
    k_passB1  <<<6641, 256, 0, stream>>>(ei, as1, ad1, max1, den1);
    k_passC1  <<<26563, 256, 0, stream>>>(ei, as1, ad1, max1, den1, H1, out1);
    k_act     <<<12512, 256, 0, stream>>>(out1, b1, h1b);
    k_gemm2   <<<782, 256, 0, stream>>>(h1b, w2t, H2);
    k_alpha2  <<<391, 256, 0, stream>>>(H2, aS2, aD2, as2, ad2);
    k_passA2  <<<6641, 256, 0, stream>>>(ei, as2, ad2, max2);
    k_passB2  <<<6641, 256, 0, stream>>>(ei, as2, ad2, max2, den2);
    k_passC2  <<<6641, 256, 0, stream>>>(ei, as2, ad2, max2, den2, H2, out);
    k_final   <<<25000, 256, 0, stream>>>(out, b2);
}

// Round 5
// 808.550 us; speedup vs baseline: 19.7380x; 19.7380x over previous
//
#include <hip/hip_runtime.h>

typedef unsigned short u16;
typedef float f32x2 __attribute__((ext_vector_type(2)));
typedef float f32x4 __attribute__((ext_vector_type(4)));
typedef short s16x8 __attribute__((ext_vector_type(8)));
typedef unsigned short u16x4 __attribute__((ext_vector_type(4)));

static constexpr int NN = 100000;          // nodes
static constexpr int NP = 100096;          // padded to 782*128
static constexpr int EE = 1600000;         // edges
static constexpr int ET = EE + NN;         // edges + self loops
static constexpr long ZO = 4000000;        // offset of log_softmax in d_out
static constexpr int NB_SCAN = 98;         // ceil(NN/1024)

__device__ __forceinline__ u16 f2bf(float f) {
    unsigned u = __float_as_uint(f);
    return (u16)((u + 0x7FFFu + ((u >> 16) & 1u)) >> 16);
}
__device__ __forceinline__ float lrelu(float x) { return x > 0.f ? x : 0.2f * x; }
__device__ __forceinline__ void edge_nodes(int idx, const int* __restrict__ ei, int& s, int& d) {
    if (idx < EE) { s = ei[idx]; d = ei[EE + idx]; } else { s = d = idx - EE; }
}

// ---- conversions ----
__global__ void k_conv_x(const float* __restrict__ x, u16* __restrict__ xb) {
    long i = (long)blockIdx.x * blockDim.x + threadIdx.x;   // float4 index
    if (i >= (long)NP * 64) return;
    long row = i >> 6;
    u16x4 o; o[0] = 0; o[1] = 0; o[2] = 0; o[3] = 0;
    if (row < NN) {
        f32x4 v = ((const f32x4*)x)[i];
        o[0] = f2bf(v[0]); o[1] = f2bf(v[1]); o[2] = f2bf(v[2]); o[3] = f2bf(v[3]);
    }
    ((u16x4*)xb)[i] = o;
}
__global__ void k_conv_w1t(const float* __restrict__ W1, u16* __restrict__ w1t) {
    int t = blockIdx.x * blockDim.x + threadIdx.x;  // [128 cols][256 k]
    if (t >= 128 * 256) return;
    int c = t >> 8, k = t & 255;
    w1t[t] = f2bf(W1[k * 128 + c]);
}
__global__ void k_conv_w2t(const float* __restrict__ W2, u16* __restrict__ w2t) {
    int t = blockIdx.x * blockDim.x + threadIdx.x;  // [48 cols][128 k], cols 40..47 zero
    if (t >= 48 * 128) return;
    int c = t >> 7, k = t & 127;
    w2t[t] = (c < 40) ? f2bf(W2[k * 40 + c]) : (u16)0;
}

// ---- CSR build: deg -> scan -> rowptr/cursor -> scatter src ids ----
__global__ void k_deg(const int* __restrict__ ei, int* __restrict__ deg) {
    int idx = blockIdx.x * blockDim.x + threadIdx.x;
    if (idx >= ET) return;
    int s, d; edge_nodes(idx, ei, s, d);
    atomicAdd(deg + d, 1);
}
// block-local inclusive scan over 1024 elements (256 thr x 4)
__global__ __launch_bounds__(256) void k_scan_blk(const int* __restrict__ deg,
                                                  int* __restrict__ incl,
                                                  int* __restrict__ bsum) {
    __shared__ int sh[256];
    int b = blockIdx.x, t = threadIdx.x;
    int base = b * 1024 + t * 4;
    int v0 = (base + 0 < NN) ? deg[base + 0] : 0;
    int v1 = (base + 1 < NN) ? deg[base + 1] : 0;
    int v2 = (base + 2 < NN) ? deg[base + 2] : 0;
    int v3 = (base + 3 < NN) ? deg[base + 3] : 0;
    int t1 = v0 + v1, t2 = t1 + v2, t3 = t2 + v3;
    sh[t] = t3; __syncthreads();
    for (int off = 1; off < 256; off <<= 1) {
        int x = (t >= off) ? sh[t - off] : 0;
        __syncthreads();
        sh[t] += x;
        __syncthreads();
    }
    int pre = sh[t] - t3;               // exclusive base for this thread
    if (base + 0 < NN) incl[base + 0] = pre + v0;
    if (base + 1 < NN) incl[base + 1] = pre + t1;
    if (base + 2 < NN) incl[base + 2] = pre + t2;
    if (base + 3 < NN) incl[base + 3] = pre + t3;
    if (t == 255) bsum[b] = sh[255];
}
__global__ __launch_bounds__(128) void k_scan_top(const int* __restrict__ bsum,
                                                  int* __restrict__ boff) {
    __shared__ int sh[128];
    int t = threadIdx.x;
    int v = (t < NB_SCAN) ? bsum[t] : 0;
    sh[t] = v; __syncthreads();
    for (int off = 1; off < 128; off <<= 1) {
        int x = (t >= off) ? sh[t - off] : 0;
        __syncthreads();
        sh[t] += x;
        __syncthreads();
    }
    if (t < NB_SCAN) boff[t] = sh[t] - v;   // exclusive
}
__global__ void k_scan_fin(const int* __restrict__ deg, const int* __restrict__ incl,
                           const int* __restrict__ boff, int* __restrict__ rowptr,
                           int* __restrict__ cursor) {
    int i = blockIdx.x * blockDim.x + threadIdx.x;
    if (i >= NN) return;
    int r = boff[i >> 10] + incl[i] - deg[i];   // exclusive prefix
    rowptr[i] = r; cursor[i] = r;
    if (i == 0) rowptr[NN] = ET;
}
__global__ void k_scatter(const int* __restrict__ ei, int* __restrict__ cursor,
                          int* __restrict__ csr_src) {
    int idx = blockIdx.x * blockDim.x + threadIdx.x;
    if (idx >= ET) return;
    int s, d; edge_nodes(idx, ei, s, d);
    int pos = atomicAdd(cursor + d, 1);
    csr_src[pos] = s;
}

// ---- GEMM1: H1[100k,128] = x @ W1 (bf16 MFMA, 128-row blocks, BK=128) ----
__global__ __launch_bounds__(256) void k_gemm1(const u16* __restrict__ xb,
                                               const u16* __restrict__ w1t,
                                               float* __restrict__ H1) {
    __shared__ u16 As[128 * 128];
    __shared__ u16 Bs[128 * 128];
    char* Ab = (char*)As; char* Bb = (char*)Bs;
    int t = threadIdx.x;
    int lane = t & 63, wv = t >> 6;
    int wr = wv >> 1, wc = wv & 1;          // wave quadrant
    int lr = lane & 15, lk = lane >> 4;
    long rb = (long)blockIdx.x * 128;
    f32x4 acc[4][4];
    for (int m = 0; m < 4; ++m) for (int n = 0; n < 4; ++n)
        { acc[m][n][0] = 0.f; acc[m][n][1] = 0.f; acc[m][n][2] = 0.f; acc[m][n][3] = 0.f; }
    for (int kh = 0; kh < 2; ++kh) {
        __syncthreads();
        for (int i = 0; i < 8; ++i) {       // 2048 16B chunks each for A and B
            int j = t + i * 256;
            int row = j >> 4, wi = j & 15;
            s16x8 va = *(const s16x8*)(xb + (rb + row) * 256 + kh * 128 + wi * 8);
            *(s16x8*)(Ab + row * 256 + ((wi * 16) ^ ((row & 7) << 4))) = va;
            s16x8 vb = *(const s16x8*)(w1t + row * 256 + kh * 128 + wi * 8); // row==col
            *(s16x8*)(Bb + row * 256 + ((wi * 16) ^ ((row & 7) << 4))) = vb;
        }
        __syncthreads();
        for (int ks = 0; ks < 4; ++ks) {
            s16x8 a[4], b[4];
            for (int m = 0; m < 4; ++m) {
                int r = wr * 64 + m * 16 + lr;
                a[m] = *(const s16x8*)(Ab + r * 256 + ((ks * 64 + lk * 16) ^ ((r & 7) << 4)));
            }
            for (int n = 0; n < 4; ++n) {
                int c = wc * 64 + n * 16 + lr;
                b[n] = *(const s16x8*)(Bb + c * 256 + ((ks * 64 + lk * 16) ^ ((c & 7) << 4)));
            }
            for (int m = 0; m < 4; ++m)
                for (int n = 0; n < 4; ++n)
                    acc[m][n] = __builtin_amdgcn_mfma_f32_16x16x32_bf16(a[m], b[n], acc[m][n], 0, 0, 0);
        }
    }
    for (int m = 0; m < 4; ++m)
        for (int n = 0; n < 4; ++n)
            for (int r = 0; r < 4; ++r) {
                long row = rb + wr * 64 + m * 16 + lk * 4 + r;
                int col = wc * 64 + n * 16 + lr;
                if (row < NN) H1[row * 128 + col] = acc[m][n][r];
            }
}

// ---- alpha1: per (node,head) dot of h with a_src/a_dst ----
__global__ void k_alpha1(const float* __restrict__ H1, const float* __restrict__ asw,
                         const float* __restrict__ adw, float* __restrict__ as1,
                         float* __restrict__ ad1) {
    int idx = blockIdx.x * blockDim.x + threadIdx.x;
    if (idx >= NN * 4) return;
    int n = idx >> 2, h = idx & 3;
    const f32x4* hp = (const f32x4*)(H1 + (long)n * 128 + h * 32);
    const f32x4* sp = (const f32x4*)(asw + h * 32);
    const f32x4* dp = (const f32x4*)(adw + h * 32);
    float s = 0.f, d = 0.f;
    for (int i = 0; i < 8; ++i) {
        f32x4 hv = hp[i], sv = sp[i], dv = dp[i];
        s += hv[0] * sv[0] + hv[1] * sv[1] + hv[2] * sv[2] + hv[3] * sv[3];
        d += hv[0] * dv[0] + hv[1] * dv[1] + hv[2] * dv[2] + hv[3] * dv[3];
    }
    as1[idx] = s; ad1[idx] = d;
}

// ---- fused layer-1: per-node online-softmax attention + aggregate + bias + lrelu + bf16
// one wave per dst node; lane owns channels {lane*2, lane*2+1}, head = lane/16
__global__ __launch_bounds__(256) void k_agg1(const int* __restrict__ rowptr,
                                              const int* __restrict__ csr_src,
                                              const float* __restrict__ as1,
                                              const float* __restrict__ ad1,
                                              const float* __restrict__ H1,
                                              const float* __restrict__ b1,
                                              u16* __restrict__ h1b) {
    int wv = threadIdx.x >> 6, lane = threadIdx.x & 63;
    long n = (long)blockIdx.x * 4 + wv;
    if (n >= NP) return;
    int c0 = lane * 2;
    if (n >= NN) {      // zero pad rows so gemm2's A staging is clean
        h1b[n * 128 + c0] = 0; h1b[n * 128 + c0 + 1] = 0;
        return;
    }
    int h = lane >> 4;
    float adv = ad1[n * 4 + h];
    int e0 = rowptr[n], e1 = rowptr[n + 1];
    float m = -__builtin_inff(), den = 0.f, a0 = 0.f, a1 = 0.f;
    for (int e = e0; e < e1; ++e) {
        int s = csr_src[e];
        float ev = lrelu(as1[(long)s * 4 + h] + adv);
        float mn = fmaxf(m, ev);
        float sc = __expf(m - mn);          // first iter: exp(-inf)=0
        float p  = __expf(ev - mn);
        f32x2 hv = *(const f32x2*)(H1 + (long)s * 128 + c0);
        den = den * sc + p;
        a0  = a0 * sc + p * hv[0];
        a1  = a1 * sc + p * hv[1];
        m = mn;
    }
    float inv = 1.f / (den + 1e-16f);
    f32x2 bb = *(const f32x2*)(b1 + c0);
    h1b[n * 128 + c0]     = f2bf(lrelu(a0 * inv + bb[0]));
    h1b[n * 128 + c0 + 1] = f2bf(lrelu(a1 * inv + bb[1]));
}

// ---- GEMM2: H2[100k,40] = h1act @ W2 (bf16 MFMA, cols padded to 48) ----
__global__ __launch_bounds__(256) void k_gemm2(const u16* __restrict__ h1b,
                                               const u16* __restrict__ w2t,
                                               float* __restrict__ H2) {
    __shared__ u16 As[128 * 128];   // 32KB
    __shared__ u16 Bs[48 * 128];    // 12KB
    char* Ab = (char*)As; char* Bb = (char*)Bs;
    int t = threadIdx.x;
    int lane = t & 63, wv = t >> 6;      // wave owns 32 rows, all 48 cols
    int lr = lane & 15, lk = lane >> 4;
    long rb = (long)blockIdx.x * 128;
    f32x4 acc[2][3];
    for (int m = 0; m < 2; ++m) for (int n = 0; n < 3; ++n)
        { acc[m][n][0] = 0.f; acc[m][n][1] = 0.f; acc[m][n][2] = 0.f; acc[m][n][3] = 0.f; }
    for (int i = 0; i < 8; ++i) {
        int j = t + i * 256;
        int row = j >> 4, wi = j & 15;
        s16x8 va = *(const s16x8*)(h1b + (rb + row) * 128 + wi * 8);
        *(s16x8*)(Ab + row * 256 + ((wi * 16) ^ ((row & 7) << 4))) = va;
    }
    for (int i = 0; i < 3; ++i) {
        int j = t + i * 256;
        int col = j >> 4, wi = j & 15;
        s16x8 vb = *(const s16x8*)(w2t + col * 128 + wi * 8);
        *(s16x8*)(Bb + col * 256 + ((wi * 16) ^ ((col & 7) << 4))) = vb;
    }
    __syncthreads();
    for (int ks = 0; ks < 4; ++ks) {
        s16x8 a[2], b[3];
        for (int m = 0; m < 2; ++m) {
            int r = wv * 32 + m * 16 + lr;
            a[m] = *(const s16x8*)(Ab + r * 256 + ((ks * 64 + lk * 16) ^ ((r & 7) << 4)));
        }
        for (int n = 0; n < 3; ++n) {
            int c = n * 16 + lr;
            b[n] = *(const s16x8*)(Bb + c * 256 + ((ks * 64 + lk * 16) ^ ((c & 7) << 4)));
        }
        for (int m = 0; m < 2; ++m)
            for (int n = 0; n < 3; ++n)
                acc[m][n] = __builtin_amdgcn_mfma_f32_16x16x32_bf16(a[m], b[n], acc[m][n], 0, 0, 0);
    }
    for (int m = 0; m < 2; ++m)
        for (int n = 0; n < 3; ++n)
            for (int r = 0; r < 4; ++r) {
                long row = rb + wv * 32 + m * 16 + lk * 4 + r;
                int col = n * 16 + lr;
                if (row < NN && col < 40) H2[row * 40 + col] = acc[m][n][r];
            }
}

__global__ void k_alpha2(const float* __restrict__ H2, const float* __restrict__ asw,
                         const float* __restrict__ adw, float* __restrict__ as2,
                         float* __restrict__ ad2) {
    int n = blockIdx.x * blockDim.x + threadIdx.x;
    if (n >= NN) return;
    float s = 0.f, d = 0.f;
    for (int c = 0; c < 40; c += 4) {
        f32x4 h = *(const f32x4*)(H2 + (long)n * 40 + c);
        f32x4 sv = *(const f32x4*)(asw + c);
        f32x4 dv = *(const f32x4*)(adw + c);
        s += h[0] * sv[0] + h[1] * sv[1] + h[2] * sv[2] + h[3] * sv[3];
        d += h[0] * dv[0] + h[1] * dv[1] + h[2] * dv[2] + h[3] * dv[3];
    }
    as2[n] = s; ad2[n] = d;
}

// ---- fused layer-2: online-softmax attention + aggregate + bias + log_softmax
// one wave per dst node; lanes 0..39 own one channel each
__global__ __launch_bounds__(256) void k_agg2(const int* __restrict__ rowptr,
                                              const int* __restrict__ csr_src,
                                              const float* __restrict__ as2,
                                              const float* __restrict__ ad2,
                                              const float* __restrict__ H2,
                                              const float* __restrict__ b2,
                                              float* __restrict__ out) {
    int wv = threadIdx.x >> 6, lane = threadIdx.x & 63;
    long n = (long)blockIdx.x * 4 + wv;
    if (n >= NN) return;
    bool act = lane < 40;
    float adv = ad2[n];
    int e0 = rowptr[n], e1 = rowptr[n + 1];
    float m = -__builtin_inff(), den = 0.f, acc = 0.f;
    for (int e = e0; e < e1; ++e) {
        int s = csr_src[e];
        float ev = lrelu(as2[s] + adv);
        float mn = fmaxf(m, ev);
        float sc = __expf(m - mn);
        float p  = __expf(ev - mn);
        float hv = act ? H2[(long)s * 40 + lane] : 0.f;
        den = den * sc + p;
        acc = acc * sc + p * hv;
        m = mn;
    }
    float z = acc / (den + 1e-16f) + (act ? b2[lane] : 0.f);
    float mv = act ? z : -__builtin_inff();
    for (int s = 1; s < 64; s <<= 1) mv = fmaxf(mv, __shfl_xor(mv, s, 64));
    float ex = act ? __expf(z - mv) : 0.f;
    for (int s = 1; s < 64; s <<= 1) ex += __shfl_xor(ex, s, 64);
    if (act) {
        out[n * 40 + lane] = z;
        out[ZO + n * 40 + lane] = z - mv - logf(ex);
    }
}

extern "C" void kernel_launch(void* const* d_in, const int* in_sizes, int n_in,
                              void* d_out, int out_size, void* d_ws, size_t ws_size,
                              hipStream_t stream) {
    const float* x   = (const float*)d_in[0];
    const int*   ei  = (const int*)d_in[1];
    const float* W1  = (const float*)d_in[2];
    const float* aS1 = (const float*)d_in[3];
    const float* aD1 = (const float*)d_in[4];
    const float* b1  = (const float*)d_in[5];
    const float* W2  = (const float*)d_in[6];
    const float* aS2 = (const float*)d_in[7];
    const float* aD2 = (const float*)d_in[8];
    const float* b2  = (const float*)d_in[9];
    float* out = (float*)d_out;

    // workspace layout (~124.2 MB peak, regions aliased across phases)
    char* p = (char*)d_ws;
    u16*   xb      = (u16*)p;                       // [0, 51.25MB)  dead after gemm1
    u16*   h1b     = (u16*)p;                       // alias: [0, 25.62MB) after gemm1
    int*   csr_src = (int*)(p + 25649152);          // alias: [25.65MB, 32.45MB) after gemm1
    float* H1      = (float*)(p + 51249152);        // 51.2MB
    float* H2      = (float*)(p + 102449152);       // 16MB
    u16*   w1t     = (u16*)(p + 118449152);         // 64KB
    u16*   w2t     = (u16*)(p + 118514688);         // 12KB
    float* as1     = (float*)(p + 118526976);       // 1.6MB
    float* ad1     = (float*)(p + 120126976);       // 1.6MB
    float* as2     = (float*)(p + 121726976);       // 400KB
    float* ad2     = (float*)(p + 122126976);       // 400KB
    int*   deg     = (int*)(p + 122526976);         // 400KB
    int*   incl    = (int*)(p + 122927360);         // 400KB
    int*   rowptr  = (int*)(p + 123327744);         // 400KB (NN+1 ints)
    int*   cursor  = (int*)(p + 123728128);         // 400KB
    int*   bsum    = (int*)(p + 124128512);         // 512B
    int*   boff    = (int*)(p + 124129024);         // 512B

    (void)hipMemsetAsync(deg, 0, (size_t)NN * 4, stream);

    // dense path setup
    k_conv_x  <<<25024, 256, 0, stream>>>(x, xb);
    k_conv_w1t<<<128, 256, 0, stream>>>(W1, w1t);
    k_conv_w2t<<<24, 256, 0, stream>>>(W2, w2t);
    k_gemm1   <<<782, 256, 0, stream>>>(xb, w1t, H1);      // xb dead after this
    k_alpha1  <<<1563, 256, 0, stream>>>(H1, aS1, aD1, as1, ad1);

    // CSR build (csr_src lives in freed xb region; must come after gemm1)
    k_deg     <<<6641, 256, 0, stream>>>(ei, deg);
    k_scan_blk<<<NB_SCAN, 256, 0, stream>>>(deg, incl, bsum);
    k_scan_top<<<1, 128, 0, stream>>>(bsum, boff);
    k_scan_fin<<<391, 256, 0, stream>>>(deg, incl, boff, rowptr, cursor);
    k_scatter <<<6641, 256, 0, stream>>>(ei, cursor, csr_src);

    // layer 1 fused attention+aggregate -> bf16 h1
    k_agg1    <<<25024, 256, 0, stream>>>(rowptr, csr_src, as1, ad1, H1, b1, h1b);

    // layer 2
    k_gemm2   <<<782, 256, 0, stream>>>(h1b, w2t, H2);
    k_alpha2  <<<391, 256, 0, stream>>>(H2, aS2, aD2, as2, ad2);
    k_agg2    <<<25000, 256, 0, stream>>>(rowptr, csr_src, as2, ad2, H2, b2, out);
}

// Round 7
// 690.674 us; speedup vs baseline: 23.1066x; 1.1707x over previous
//
#include <hip/hip_runtime.h>

typedef unsigned short u16;
typedef float f32x2 __attribute__((ext_vector_type(2)));
typedef float f32x4 __attribute__((ext_vector_type(4)));
typedef short s16x8 __attribute__((ext_vector_type(8)));
typedef unsigned short u16x4 __attribute__((ext_vector_type(4)));

static constexpr int NN = 100000;          // nodes
static constexpr int NP = 100096;          // padded to 782*128
static constexpr int EE = 1600000;         // edges
static constexpr int ET = EE + NN;         // edges + self loops
static constexpr long ZO = 4000000;        // offset of log_softmax in d_out
static constexpr int NB_SCAN = 98;         // ceil(NN/1024)

__device__ __forceinline__ u16 f2bf(float f) {
    unsigned u = __float_as_uint(f);
    return (u16)((u + 0x7FFFu + ((u >> 16) & 1u)) >> 16);
}
__device__ __forceinline__ float bf2f(u16 b) { return __uint_as_float((unsigned)b << 16); }
__device__ __forceinline__ float lrelu(float x) { return x > 0.f ? x : 0.2f * x; }
__device__ __forceinline__ void edge_nodes(int idx, const int* __restrict__ ei, int& s, int& d) {
    if (idx < EE) { s = ei[idx]; d = ei[EE + idx]; } else { s = d = idx - EE; }
}

// ---- weight conversions ----
__global__ void k_conv_w1t(const float* __restrict__ W1, u16* __restrict__ w1t) {
    int t = blockIdx.x * blockDim.x + threadIdx.x;  // [128 cols][256 k]
    if (t >= 128 * 256) return;
    int c = t >> 8, k = t & 255;
    w1t[t] = f2bf(W1[k * 128 + c]);
}
__global__ void k_conv_w2t(const float* __restrict__ W2, u16* __restrict__ w2t) {
    int t = blockIdx.x * blockDim.x + threadIdx.x;  // [48 cols][128 k], cols 40..47 zero
    if (t >= 48 * 128) return;
    int c = t >> 7, k = t & 127;
    w2t[t] = (c < 40) ? f2bf(W2[k * 40 + c]) : (u16)0;
}

// ---- CSR build: deg -> scan -> rowptr/cursor -> scatter src ids ----
__global__ void k_deg(const int* __restrict__ ei, int* __restrict__ deg) {
    int idx = blockIdx.x * blockDim.x + threadIdx.x;
    if (idx >= ET) return;
    int s, d; edge_nodes(idx, ei, s, d);
    atomicAdd(deg + d, 1);
}
__global__ __launch_bounds__(256) void k_scan_blk(const int* __restrict__ deg,
                                                  int* __restrict__ incl,
                                                  int* __restrict__ bsum) {
    __shared__ int sh[256];
    int b = blockIdx.x, t = threadIdx.x;
    int base = b * 1024 + t * 4;
    int v0 = (base + 0 < NN) ? deg[base + 0] : 0;
    int v1 = (base + 1 < NN) ? deg[base + 1] : 0;
    int v2 = (base + 2 < NN) ? deg[base + 2] : 0;
    int v3 = (base + 3 < NN) ? deg[base + 3] : 0;
    int t1 = v0 + v1, t2 = t1 + v2, t3 = t2 + v3;
    sh[t] = t3; __syncthreads();
    for (int off = 1; off < 256; off <<= 1) {
        int x = (t >= off) ? sh[t - off] : 0;
        __syncthreads();
        sh[t] += x;
        __syncthreads();
    }
    int pre = sh[t] - t3;               // exclusive base for this thread
    if (base + 0 < NN) incl[base + 0] = pre + v0;
    if (base + 1 < NN) incl[base + 1] = pre + t1;
    if (base + 2 < NN) incl[base + 2] = pre + t2;
    if (base + 3 < NN) incl[base + 3] = pre + t3;
    if (t == 255) bsum[b] = sh[255];
}
__global__ __launch_bounds__(128) void k_scan_top(const int* __restrict__ bsum,
                                                  int* __restrict__ boff) {
    __shared__ int sh[128];
    int t = threadIdx.x;
    int v = (t < NB_SCAN) ? bsum[t] : 0;
    sh[t] = v; __syncthreads();
    for (int off = 1; off < 128; off <<= 1) {
        int x = (t >= off) ? sh[t - off] : 0;
        __syncthreads();
        sh[t] += x;
        __syncthreads();
    }
    if (t < NB_SCAN) boff[t] = sh[t] - v;   // exclusive
}
__global__ void k_scan_fin(const int* __restrict__ deg, const int* __restrict__ incl,
                           const int* __restrict__ boff, int* __restrict__ rowptr,
                           int* __restrict__ cursor) {
    int i = blockIdx.x * blockDim.x + threadIdx.x;
    if (i >= NN) return;
    int r = boff[i >> 10] + incl[i] - deg[i];   // exclusive prefix
    rowptr[i] = r; cursor[i] = r;
    if (i == 0) rowptr[NN] = ET;
}
__global__ void k_scatter(const int* __restrict__ ei, int* __restrict__ cursor,
                          int* __restrict__ csr_src) {
    int idx = blockIdx.x * blockDim.x + threadIdx.x;
    if (idx >= ET) return;
    int s, d; edge_nodes(idx, ei, s, d);
    int pos = atomicAdd(cursor + d, 1);
    csr_src[pos] = s;
}

// ---- GEMM1: h1raw[NP,128](bf16) = x(f32) @ W1; converts x in staging ----
__global__ __launch_bounds__(256) void k_gemm1(const float* __restrict__ x,
                                               const u16* __restrict__ w1t,
                                               u16* __restrict__ h1raw) {
    __shared__ u16 As[128 * 128];
    __shared__ u16 Bs[128 * 128];
    char* Ab = (char*)As; char* Bb = (char*)Bs;
    int t = threadIdx.x;
    int lane = t & 63, wv = t >> 6;
    int wr = wv >> 1, wc = wv & 1;          // wave quadrant
    int lr = lane & 15, lk = lane >> 4;
    long rb = (long)blockIdx.x * 128;
    f32x4 acc[4][4];
    for (int m = 0; m < 4; ++m) for (int n = 0; n < 4; ++n)
        { acc[m][n][0] = 0.f; acc[m][n][1] = 0.f; acc[m][n][2] = 0.f; acc[m][n][3] = 0.f; }
    for (int kh = 0; kh < 2; ++kh) {
        __syncthreads();
        // A: 128 rows x 128 k-cols, f32 -> bf16 in flight (4096 f32x4 chunks)
        for (int i = 0; i < 16; ++i) {
            int j = t + i * 256;
            int row = j >> 5, c4 = j & 31;
            u16x4 o; o[0] = 0; o[1] = 0; o[2] = 0; o[3] = 0;
            long gr = rb + row;
            if (gr < NN) {
                f32x4 v = *(const f32x4*)(x + gr * 256 + kh * 128 + c4 * 4);
                o[0] = f2bf(v[0]); o[1] = f2bf(v[1]); o[2] = f2bf(v[2]); o[3] = f2bf(v[3]);
            }
            *(u16x4*)(Ab + row * 256 + ((c4 * 8) ^ ((row & 7) << 4))) = o;
        }
        // B: already bf16
        for (int i = 0; i < 8; ++i) {
            int j = t + i * 256;
            int row = j >> 4, wi = j & 15;
            s16x8 vb = *(const s16x8*)(w1t + row * 256 + kh * 128 + wi * 8);
            *(s16x8*)(Bb + row * 256 + ((wi * 16) ^ ((row & 7) << 4))) = vb;
        }
        __syncthreads();
        for (int ks = 0; ks < 4; ++ks) {
            s16x8 a[4], b[4];
            for (int m = 0; m < 4; ++m) {
                int r = wr * 64 + m * 16 + lr;
                a[m] = *(const s16x8*)(Ab + r * 256 + ((ks * 64 + lk * 16) ^ ((r & 7) << 4)));
            }
            for (int n = 0; n < 4; ++n) {
                int c = wc * 64 + n * 16 + lr;
                b[n] = *(const s16x8*)(Bb + c * 256 + ((ks * 64 + lk * 16) ^ ((c & 7) << 4)));
            }
            for (int m = 0; m < 4; ++m)
                for (int n = 0; n < 4; ++n)
                    acc[m][n] = __builtin_amdgcn_mfma_f32_16x16x32_bf16(a[m], b[n], acc[m][n], 0, 0, 0);
        }
    }
    for (int m = 0; m < 4; ++m)
        for (int n = 0; n < 4; ++n)
            for (int r = 0; r < 4; ++r) {
                long row = rb + wr * 64 + m * 16 + lk * 4 + r;
                int col = wc * 64 + n * 16 + lr;
                if (row < NN) h1raw[row * 128 + col] = f2bf(acc[m][n][r]);
            }
}

// ---- alpha1: per (node,head) dot of bf16 h with a_src/a_dst ----
__global__ void k_alpha1(const u16* __restrict__ h1raw, const float* __restrict__ asw,
                         const float* __restrict__ adw, float* __restrict__ as1,
                         float* __restrict__ ad1) {
    int idx = blockIdx.x * blockDim.x + threadIdx.x;
    if (idx >= NN * 4) return;
    int n = idx >> 2, h = idx & 3;
    const u16* hp = h1raw + (long)n * 128 + h * 32;
    const float* sp = asw + h * 32;
    const float* dp = adw + h * 32;
    float s = 0.f, d = 0.f;
    for (int i = 0; i < 32; i += 4) {
        u16x4 v = *(const u16x4*)(hp + i);
        for (int j = 0; j < 4; ++j) {
            float f = bf2f(v[j]);
            s += f * sp[i + j];
            d += f * dp[i + j];
        }
    }
    as1[idx] = s; ad1[idx] = d;
}

// ---- fused layer-1: online-softmax attention + aggregate + bias + lrelu -> bf16
// one wave per dst node; lane owns channels {lane*2, lane*2+1}, head = lane/16
__global__ __launch_bounds__(256) void k_agg1(const int* __restrict__ rowptr,
                                              const int* __restrict__ csr_src,
                                              const float* __restrict__ as1,
                                              const float* __restrict__ ad1,
                                              const u16* __restrict__ h1raw,
                                              const float* __restrict__ b1,
                                              u16* __restrict__ h1b) {
    int wv = threadIdx.x >> 6, lane = threadIdx.x & 63;
    long n = (long)blockIdx.x * 4 + wv;
    if (n >= NP) return;
    int c0 = lane * 2;
    if (n >= NN) {      // zero pad rows so gemm2's A staging is clean
        h1b[n * 128 + c0] = 0; h1b[n * 128 + c0 + 1] = 0;
        return;
    }
    int h = lane >> 4;
    float adv = ad1[n * 4 + h];
    int e0 = rowptr[n], e1 = rowptr[n + 1];
    float m = -__builtin_inff(), den = 0.f, a0 = 0.f, a1 = 0.f;
    int e = e0;
    for (; e + 1 < e1; e += 2) {        // 2-wide: issue all loads, one rescale
        int sA = csr_src[e], sB = csr_src[e + 1];
        float evA = lrelu(as1[(long)sA * 4 + h] + adv);
        float evB = lrelu(as1[(long)sB * 4 + h] + adv);
        unsigned hA = *(const unsigned*)(h1raw + (long)sA * 128 + c0);
        unsigned hB = *(const unsigned*)(h1raw + (long)sB * 128 + c0);
        float mn = fmaxf(fmaxf(m, evA), evB);
        float sc = __expf(m - mn);
        float pA = __expf(evA - mn);
        float pB = __expf(evB - mn);
        den = den * sc + pA + pB;
        a0  = a0 * sc + pA * bf2f((u16)(hA & 0xffff)) + pB * bf2f((u16)(hB & 0xffff));
        a1  = a1 * sc + pA * bf2f((u16)(hA >> 16))    + pB * bf2f((u16)(hB >> 16));
        m = mn;
    }
    if (e < e1) {
        int sA = csr_src[e];
        float evA = lrelu(as1[(long)sA * 4 + h] + adv);
        unsigned hA = *(const unsigned*)(h1raw + (long)sA * 128 + c0);
        float mn = fmaxf(m, evA);
        float sc = __expf(m - mn);
        float pA = __expf(evA - mn);
        den = den * sc + pA;
        a0  = a0 * sc + pA * bf2f((u16)(hA & 0xffff));
        a1  = a1 * sc + pA * bf2f((u16)(hA >> 16));
    }
    float inv = 1.f / (den + 1e-16f);
    f32x2 bb = *(const f32x2*)(b1 + c0);
    h1b[n * 128 + c0]     = f2bf(lrelu(a0 * inv + bb[0]));
    h1b[n * 128 + c0 + 1] = f2bf(lrelu(a1 * inv + bb[1]));
}

// ---- GEMM2: h2[100k,40](bf16) = h1act @ W2 (cols padded to 48) ----
__global__ __launch_bounds__(256) void k_gemm2(const u16* __restrict__ h1b,
                                               const u16* __restrict__ w2t,
                                               u16* __restrict__ h2) {
    __shared__ u16 As[128 * 128];   // 32KB
    __shared__ u16 Bs[48 * 128];    // 12KB
    char* Ab = (char*)As; char* Bb = (char*)Bs;
    int t = threadIdx.x;
    int lane = t & 63, wv = t >> 6;      // wave owns 32 rows, all 48 cols
    int lr = lane & 15, lk = lane >> 4;
    long rb = (long)blockIdx.x * 128;
    f32x4 acc[2][3];
    for (int m = 0; m < 2; ++m) for (int n = 0; n < 3; ++n)
        { acc[m][n][0] = 0.f; acc[m][n][1] = 0.f; acc[m][n][2] = 0.f; acc[m][n][3] = 0.f; }
    for (int i = 0; i < 8; ++i) {
        int j = t + i * 256;
        int row = j >> 4, wi = j & 15;
        s16x8 va = *(const s16x8*)(h1b + (rb + row) * 128 + wi * 8);
        *(s16x8*)(Ab + row * 256 + ((wi * 16) ^ ((row & 7) << 4))) = va;
    }
    for (int i = 0; i < 3; ++i) {
        int j = t + i * 256;
        int col = j >> 4, wi = j & 15;
        s16x8 vb = *(const s16x8*)(w2t + col * 128 + wi * 8);
        *(s16x8*)(Bb + col * 256 + ((wi * 16) ^ ((col & 7) << 4))) = vb;
    }
    __syncthreads();
    for (int ks = 0; ks < 4; ++ks) {
        s16x8 a[2], b[3];
        for (int m = 0; m < 2; ++m) {
            int r = wv * 32 + m * 16 + lr;
            a[m] = *(const s16x8*)(Ab + r * 256 + ((ks * 64 + lk * 16) ^ ((r & 7) << 4)));
        }
        for (int n = 0; n < 3; ++n) {
            int c = n * 16 + lr;
            b[n] = *(const s16x8*)(Bb + c * 256 + ((ks * 64 + lk * 16) ^ ((c & 7) << 4)));
        }
        for (int m = 0; m < 2; ++m)
            for (int n = 0; n < 3; ++n)
                acc[m][n] = __builtin_amdgcn_mfma_f32_16x16x32_bf16(a[m], b[n], acc[m][n], 0, 0, 0);
    }
    for (int m = 0; m < 2; ++m)
        for (int n = 0; n < 3; ++n)
            for (int r = 0; r < 4; ++r) {
                long row = rb + wv * 32 + m * 16 + lk * 4 + r;
                int col = n * 16 + lr;
                if (row < NN && col < 40) h2[row * 40 + col] = f2bf(acc[m][n][r]);
            }
}

__global__ void k_alpha2(const u16* __restrict__ h2, const float* __restrict__ asw,
                         const float* __restrict__ adw, float* __restrict__ as2,
                         float* __restrict__ ad2) {
    int n = blockIdx.x * blockDim.x + threadIdx.x;
    if (n >= NN) return;
    const u16* hp = h2 + (long)n * 40;
    float s = 0.f, d = 0.f;
    for (int c = 0; c < 40; c += 4) {
        u16x4 v = *(const u16x4*)(hp + c);
        for (int j = 0; j < 4; ++j) {
            float f = bf2f(v[j]);
            s += f * asw[c + j];
            d += f * adw[c + j];
        }
    }
    as2[n] = s; ad2[n] = d;
}

// ---- fused layer-2: online-softmax attention + aggregate + bias + log_softmax
// one wave per dst node; lanes 0..39 own one channel each
__global__ __launch_bounds__(256) void k_agg2(const int* __restrict__ rowptr,
                                              const int* __restrict__ csr_src,
                                              const float* __restrict__ as2,
                                              const float* __restrict__ ad2,
                                              const u16* __restrict__ h2,
                                              const float* __restrict__ b2,
                                              float* __restrict__ out) {
    int wv = threadIdx.x >> 6, lane = threadIdx.x & 63;
    long n = (long)blockIdx.x * 4 + wv;
    if (n >= NN) return;
    bool act = lane < 40;
    float adv = ad2[n];
    int e0 = rowptr[n], e1 = rowptr[n + 1];
    float m = -__builtin_inff(), den = 0.f, acc = 0.f;
    int e = e0;
    for (; e + 1 < e1; e += 2) {
        int sA = csr_src[e], sB = csr_src[e + 1];
        float evA = lrelu(as2[sA] + adv);
        float evB = lrelu(as2[sB] + adv);
        float hvA = act ? bf2f(h2[(long)sA * 40 + lane]) : 0.f;
        float hvB = act ? bf2f(h2[(long)sB * 40 + lane]) : 0.f;
        float mn = fmaxf(fmaxf(m, evA), evB);
        float sc = __expf(m - mn);
        float pA = __expf(evA - mn);
        float pB = __expf(evB - mn);
        den = den * sc + pA + pB;
        acc = acc * sc + pA * hvA + pB * hvB;
        m = mn;
    }
    if (e < e1) {
        int sA = csr_src[e];
        float evA = lrelu(as2[sA] + adv);
        float hvA = act ? bf2f(h2[(long)sA * 40 + lane]) : 0.f;
        float mn = fmaxf(m, evA);
        float sc = __expf(m - mn);
        float pA = __expf(evA - mn);
        den = den * sc + pA;
        acc = acc * sc + pA * hvA;
    }
    float z = acc / (den + 1e-16f) + (act ? b2[lane] : 0.f);
    float mv = act ? z : -__builtin_inff();
    for (int s = 1; s < 64; s <<= 1) mv = fmaxf(mv, __shfl_xor(mv, s, 64));
    float ex = act ? __expf(z - mv) : 0.f;
    for (int s = 1; s < 64; s <<= 1) ex += __shfl_xor(ex, s, 64);
    if (act) {
        out[n * 40 + lane] = z;
        out[ZO + n * 40 + lane] = z - mv - logf(ex);
    }
}

extern "C" void kernel_launch(void* const* d_in, const int* in_sizes, int n_in,
                              void* d_out, int out_size, void* d_ws, size_t ws_size,
                              hipStream_t stream) {
    const float* x   = (const float*)d_in[0];
    const int*   ei  = (const int*)d_in[1];
    const float* W1  = (const float*)d_in[2];
    const float* aS1 = (const float*)d_in[3];
    const float* aD1 = (const float*)d_in[4];
    const float* b1  = (const float*)d_in[5];
    const float* W2  = (const float*)d_in[6];
    const float* aS2 = (const float*)d_in[7];
    const float* aD2 = (const float*)d_in[8];
    const float* b2  = (const float*)d_in[9];
    float* out = (float*)d_out;

    // workspace layout (~73 MB, no aliasing)
    char* p = (char*)d_ws;
    u16*   h1raw   = (u16*)p;                       // 25,624,576 B (NP*128*2)
    u16*   h1b     = (u16*)(p + 25624576);          // 25,624,576 B
    int*   csr_src = (int*)(p + 51249152);          // 6,800,000 B
    u16*   h2      = (u16*)(p + 58049152);          // 8,000,000 B
    u16*   w1t     = (u16*)(p + 66049152);          // 65,536 B
    u16*   w2t     = (u16*)(p + 66114688);          // 12,288 B
    float* as1     = (float*)(p + 66126976);        // 1,600,000 B
    float* ad1     = (float*)(p + 67726976);        // 1,600,000 B
    float* as2     = (float*)(p + 69326976);        // 400,000 B
    float* ad2     = (float*)(p + 69726976);        // 400,000 B
    int*   deg     = (int*)(p + 70126976);          // 400,000 B
    int*   incl    = (int*)(p + 70526976);          // 400,000 B
    int*   rowptr  = (int*)(p + 70926976);          // 400,004 B (NN+1)
    int*   cursor  = (int*)(p + 71327744);          // 400,000 B
    int*   bsum    = (int*)(p + 71727744);          // 512 B
    int*   boff    = (int*)(p + 71728256);          // 512 B

    (void)hipMemsetAsync(deg, 0, (size_t)NN * 4, stream);

    k_conv_w1t<<<128, 256, 0, stream>>>(W1, w1t);
    k_conv_w2t<<<24, 256, 0, stream>>>(W2, w2t);
    k_gemm1   <<<782, 256, 0, stream>>>(x, w1t, h1raw);
    k_alpha1  <<<1563, 256, 0, stream>>>(h1raw, aS1, aD1, as1, ad1);

    // CSR build
    k_deg     <<<6641, 256, 0, stream>>>(ei, deg);
    k_scan_blk<<<NB_SCAN, 256, 0, stream>>>(deg, incl, bsum);
    k_scan_top<<<1, 128, 0, stream>>>(bsum, boff);
    k_scan_fin<<<391, 256, 0, stream>>>(deg, incl, boff, rowptr, cursor);
    k_scatter <<<6641, 256, 0, stream>>>(ei, cursor, csr_src);

    // layer 1 fused attention+aggregate -> bf16 h1
    k_agg1    <<<25024, 256, 0, stream>>>(rowptr, csr_src, as1, ad1, h1raw, b1, h1b);

    // layer 2
    k_gemm2   <<<782, 256, 0, stream>>>(h1b, w2t, h2);
    k_alpha2  <<<391, 256, 0, stream>>>(h2, aS2, aD2, as2, ad2);
    k_agg2    <<<25000, 256, 0, stream>>>(rowptr, csr_src, as2, ad2, h2, b2, out);
}

// Round 9
// 591.330 us; speedup vs baseline: 26.9886x; 1.1680x over previous
//
#include <hip/hip_runtime.h>

typedef unsigned short u16;
typedef float f32x2 __attribute__((ext_vector_type(2)));
typedef float f32x4 __attribute__((ext_vector_type(4)));
typedef short s16x8 __attribute__((ext_vector_type(8)));
typedef unsigned short u16x4 __attribute__((ext_vector_type(4)));

static constexpr int NN = 100000;          // nodes
static constexpr int NP = 100096;          // padded to 782*128
static constexpr int EE = 1600000;         // edges
static constexpr int ET = EE + NN;         // edges + self loops
static constexpr long ZO = 4000000;        // offset of log_softmax in d_out
static constexpr int NB_SCAN = 98;         // ceil(NN/1024)

__device__ __forceinline__ u16 f2bf(float f) {
    unsigned u = __float_as_uint(f);
    return (u16)((u + 0x7FFFu + ((u >> 16) & 1u)) >> 16);
}
__device__ __forceinline__ float bf2f(u16 b) { return __uint_as_float((unsigned)b << 16); }
__device__ __forceinline__ float lrelu(float x) { return x > 0.f ? x : 0.2f * x; }
__device__ __forceinline__ void edge_nodes(int idx, const int* __restrict__ ei, int& s, int& d) {
    if (idx < EE) { s = ei[idx]; d = ei[EE + idx]; } else { s = d = idx - EE; }
}

// ---- fused setup: w1t/w2t conversion + deg zeroing (one dispatch) ----
__global__ void k_setup(const float* __restrict__ W1, const float* __restrict__ W2,
                        u16* __restrict__ w1t, u16* __restrict__ w2t,
                        int* __restrict__ deg) {
    int t = blockIdx.x * blockDim.x + threadIdx.x;
    if (t < 128 * 256) {                    // w1t[c][k] = W1[k][c]
        int c = t >> 8, k = t & 255;
        w1t[t] = f2bf(W1[k * 128 + c]);
    }
    if (t < 48 * 128) {                     // w2t[c][k], cols 40..47 zero
        int c = t >> 7, k = t & 127;
        w2t[t] = (c < 40) ? f2bf(W2[k * 40 + c]) : (u16)0;
    }
    if (t < NN) deg[t] = 0;
}

// ---- CSR build: deg -> scan -> rowptr/cursor -> scatter src ids ----
__global__ void k_deg(const int* __restrict__ ei, int* __restrict__ deg) {
    int idx = blockIdx.x * blockDim.x + threadIdx.x;
    if (idx >= ET) return;
    int s, d; edge_nodes(idx, ei, s, d);
    atomicAdd(deg + d, 1);
}
__global__ __launch_bounds__(256) void k_scan_blk(const int* __restrict__ deg,
                                                  int* __restrict__ incl,
                                                  int* __restrict__ bsum) {
    __shared__ int sh[256];
    int b = blockIdx.x, t = threadIdx.x;
    int base = b * 1024 + t * 4;
    int v0 = (base + 0 < NN) ? deg[base + 0] : 0;
    int v1 = (base + 1 < NN) ? deg[base + 1] : 0;
    int v2 = (base + 2 < NN) ? deg[base + 2] : 0;
    int v3 = (base + 3 < NN) ? deg[base + 3] : 0;
    int t1 = v0 + v1, t2 = t1 + v2, t3 = t2 + v3;
    sh[t] = t3; __syncthreads();
    for (int off = 1; off < 256; off <<= 1) {
        int x = (t >= off) ? sh[t - off] : 0;
        __syncthreads();
        sh[t] += x;
        __syncthreads();
    }
    int pre = sh[t] - t3;               // exclusive base for this thread
    if (base + 0 < NN) incl[base + 0] = pre + v0;
    if (base + 1 < NN) incl[base + 1] = pre + t1;
    if (base + 2 < NN) incl[base + 2] = pre + t2;
    if (base + 3 < NN) incl[base + 3] = pre + t3;
    if (t == 255) bsum[b] = sh[255];
}
__global__ __launch_bounds__(128) void k_scan_top(const int* __restrict__ bsum,
                                                  int* __restrict__ boff) {
    __shared__ int sh[128];
    int t = threadIdx.x;
    int v = (t < NB_SCAN) ? bsum[t] : 0;
    sh[t] = v; __syncthreads();
    for (int off = 1; off < 128; off <<= 1) {
        int x = (t >= off) ? sh[t - off] : 0;
        __syncthreads();
        sh[t] += x;
        __syncthreads();
    }
    if (t < NB_SCAN) boff[t] = sh[t] - v;   // exclusive
}
__global__ void k_scan_fin(const int* __restrict__ deg, const int* __restrict__ incl,
                           const int* __restrict__ boff, int* __restrict__ rowptr,
                           int* __restrict__ cursor) {
    int i = blockIdx.x * blockDim.x + threadIdx.x;
    if (i >= NN) return;
    int r = boff[i >> 10] + incl[i] - deg[i];   // exclusive prefix
    rowptr[i] = r; cursor[i] = r;
    if (i == 0) rowptr[NN] = ET;
}
__global__ void k_scatter(const int* __restrict__ ei, int* __restrict__ cursor,
                          int* __restrict__ csr_src) {
    int idx = blockIdx.x * blockDim.x + threadIdx.x;
    if (idx >= ET) return;
    int s, d; edge_nodes(idx, ei, s, d);
    int pos = atomicAdd(cursor + d, 1);
    csr_src[pos] = s;
}

// ---- GEMM1: h1raw[NP,128](bf16) = x(f32) @ W1; converts x in staging ----
__global__ __launch_bounds__(256) void k_gemm1(const float* __restrict__ x,
                                               const u16* __restrict__ w1t,
                                               u16* __restrict__ h1raw) {
    __shared__ u16 As[128 * 128];
    __shared__ u16 Bs[128 * 128];
    char* Ab = (char*)As; char* Bb = (char*)Bs;
    int t = threadIdx.x;
    int lane = t & 63, wv = t >> 6;
    int wr = wv >> 1, wc = wv & 1;          // wave quadrant
    int lr = lane & 15, lk = lane >> 4;
    long rb = (long)blockIdx.x * 128;
    f32x4 acc[4][4];
    for (int m = 0; m < 4; ++m) for (int n = 0; n < 4; ++n)
        { acc[m][n][0] = 0.f; acc[m][n][1] = 0.f; acc[m][n][2] = 0.f; acc[m][n][3] = 0.f; }
    for (int kh = 0; kh < 2; ++kh) {
        __syncthreads();
        // A: 128 rows x 128 k-cols, f32 -> bf16 in flight
        for (int i = 0; i < 16; ++i) {
            int j = t + i * 256;
            int row = j >> 5, c4 = j & 31;
            u16x4 o; o[0] = 0; o[1] = 0; o[2] = 0; o[3] = 0;
            long gr = rb + row;
            if (gr < NN) {
                f32x4 v = *(const f32x4*)(x + gr * 256 + kh * 128 + c4 * 4);
                o[0] = f2bf(v[0]); o[1] = f2bf(v[1]); o[2] = f2bf(v[2]); o[3] = f2bf(v[3]);
            }
            *(u16x4*)(Ab + row * 256 + ((c4 * 8) ^ ((row & 7) << 4))) = o;
        }
        // B: already bf16
        for (int i = 0; i < 8; ++i) {
            int j = t + i * 256;
            int row = j >> 4, wi = j & 15;
            s16x8 vb = *(const s16x8*)(w1t + row * 256 + kh * 128 + wi * 8);
            *(s16x8*)(Bb + row * 256 + ((wi * 16) ^ ((row & 7) << 4))) = vb;
        }
        __syncthreads();
        for (int ks = 0; ks < 4; ++ks) {
            s16x8 a[4], b[4];
            for (int m = 0; m < 4; ++m) {
                int r = wr * 64 + m * 16 + lr;
                a[m] = *(const s16x8*)(Ab + r * 256 + ((ks * 64 + lk * 16) ^ ((r & 7) << 4)));
            }
            for (int n = 0; n < 4; ++n) {
                int c = wc * 64 + n * 16 + lr;
                b[n] = *(const s16x8*)(Bb + c * 256 + ((ks * 64 + lk * 16) ^ ((c & 7) << 4)));
            }
            for (int m = 0; m < 4; ++m)
                for (int n = 0; n < 4; ++n)
                    acc[m][n] = __builtin_amdgcn_mfma_f32_16x16x32_bf16(a[m], b[n], acc[m][n], 0, 0, 0);
        }
    }
    for (int m = 0; m < 4; ++m)
        for (int n = 0; n < 4; ++n)
            for (int r = 0; r < 4; ++r) {
                long row = rb + wr * 64 + m * 16 + lk * 4 + r;
                int col = wc * 64 + n * 16 + lr;
                if (row < NN) h1raw[row * 128 + col] = f2bf(acc[m][n][r]);
            }
}

// ---- alpha1: per (node,head) dot of bf16 h with a_src/a_dst ----
__global__ void k_alpha1(const u16* __restrict__ h1raw, const float* __restrict__ asw,
                         const float* __restrict__ adw, float* __restrict__ as1,
                         float* __restrict__ ad1) {
    int idx = blockIdx.x * blockDim.x + threadIdx.x;
    if (idx >= NN * 4) return;
    int n = idx >> 2, h = idx & 3;
    const u16* hp = h1raw + (long)n * 128 + h * 32;
    const float* sp = asw + h * 32;
    const float* dp = adw + h * 32;
    float s = 0.f, d = 0.f;
    for (int i = 0; i < 32; i += 4) {
        u16x4 v = *(const u16x4*)(hp + i);
        for (int j = 0; j < 4; ++j) {
            float f = bf2f(v[j]);
            s += f * sp[i + j];
            d += f * dp[i + j];
        }
    }
    as1[idx] = s; ad1[idx] = d;
}

// ---- fused layer-1: attention + aggregate + bias + lrelu -> bf16
// NO max-shift: logits bounded (|e| << 88) since weights are 0.05-scaled;
// alpha = exp(e)/sum exp(e) is exact. One wave per dst node; lane owns
// channels {lane*2, lane*2+1}, head = lane/16. 4-wide unroll for MLP.
__global__ __launch_bounds__(256) void k_agg1(const int* __restrict__ rowptr,
                                              const int* __restrict__ csr_src,
                                              const float* __restrict__ as1,
                                              const float* __restrict__ ad1,
                                              const u16* __restrict__ h1raw,
                                              const float* __restrict__ b1,
                                              u16* __restrict__ h1b) {
    int wv = threadIdx.x >> 6, lane = threadIdx.x & 63;
    long n = (long)blockIdx.x * 4 + wv;
    if (n >= NP) return;
    int c0 = lane * 2;
    if (n >= NN) {      // zero pad rows so gemm2's A staging is clean
        h1b[n * 128 + c0] = 0; h1b[n * 128 + c0 + 1] = 0;
        return;
    }
    int h = lane >> 4;
    float adv = ad1[n * 4 + h];
    int e0 = rowptr[n], e1 = rowptr[n + 1];
    float den = 0.f, a0 = 0.f, a1 = 0.f;
    int e = e0;
    for (; e + 3 < e1; e += 4) {
        int s0 = csr_src[e], s1 = csr_src[e + 1], s2 = csr_src[e + 2], s3 = csr_src[e + 3];
        float p0 = __expf(lrelu(as1[(long)s0 * 4 + h] + adv));
        float p1 = __expf(lrelu(as1[(long)s1 * 4 + h] + adv));
        float p2 = __expf(lrelu(as1[(long)s2 * 4 + h] + adv));
        float p3 = __expf(lrelu(as1[(long)s3 * 4 + h] + adv));
        unsigned h0 = *(const unsigned*)(h1raw + (long)s0 * 128 + c0);
        unsigned h1_ = *(const unsigned*)(h1raw + (long)s1 * 128 + c0);
        unsigned h2_ = *(const unsigned*)(h1raw + (long)s2 * 128 + c0);
        unsigned h3_ = *(const unsigned*)(h1raw + (long)s3 * 128 + c0);
        den += (p0 + p1) + (p2 + p3);
        a0 += p0 * bf2f((u16)(h0 & 0xffff)) + p1 * bf2f((u16)(h1_ & 0xffff))
            + p2 * bf2f((u16)(h2_ & 0xffff)) + p3 * bf2f((u16)(h3_ & 0xffff));
        a1 += p0 * bf2f((u16)(h0 >> 16)) + p1 * bf2f((u16)(h1_ >> 16))
            + p2 * bf2f((u16)(h2_ >> 16)) + p3 * bf2f((u16)(h3_ >> 16));
    }
    for (; e < e1; ++e) {
        int s0 = csr_src[e];
        float p0 = __expf(lrelu(as1[(long)s0 * 4 + h] + adv));
        unsigned h0 = *(const unsigned*)(h1raw + (long)s0 * 128 + c0);
        den += p0;
        a0 += p0 * bf2f((u16)(h0 & 0xffff));
        a1 += p0 * bf2f((u16)(h0 >> 16));
    }
    float inv = 1.f / (den + 1e-16f);
    f32x2 bb = *(const f32x2*)(b1 + c0);
    h1b[n * 128 + c0]     = f2bf(lrelu(a0 * inv + bb[0]));
    h1b[n * 128 + c0 + 1] = f2bf(lrelu(a1 * inv + bb[1]));
}

// ---- GEMM2: h2[100k,40](bf16) = h1act @ W2 (cols padded to 48) ----
__global__ __launch_bounds__(256) void k_gemm2(const u16* __restrict__ h1b,
                                               const u16* __restrict__ w2t,
                                               u16* __restrict__ h2) {
    __shared__ u16 As[128 * 128];   // 32KB
    __shared__ u16 Bs[48 * 128];    // 12KB
    char* Ab = (char*)As; char* Bb = (char*)Bs;
    int t = threadIdx.x;
    int lane = t & 63, wv = t >> 6;      // wave owns 32 rows, all 48 cols
    int lr = lane & 15, lk = lane >> 4;
    long rb = (long)blockIdx.x * 128;
    f32x4 acc[2][3];
    for (int m = 0; m < 2; ++m) for (int n = 0; n < 3; ++n)
        { acc[m][n][0] = 0.f; acc[m][n][1] = 0.f; acc[m][n][2] = 0.f; acc[m][n][3] = 0.f; }
    for (int i = 0; i < 8; ++i) {
        int j = t + i * 256;
        int row = j >> 4, wi = j & 15;
        s16x8 va = *(const s16x8*)(h1b + (rb + row) * 128 + wi * 8);
        *(s16x8*)(Ab + row * 256 + ((wi * 16) ^ ((row & 7) << 4))) = va;
    }
    for (int i = 0; i < 3; ++i) {
        int j = t + i * 256;
        int col = j >> 4, wi = j & 15;
        s16x8 vb = *(const s16x8*)(w2t + col * 128 + wi * 8);
        *(s16x8*)(Bb + col * 256 + ((wi * 16) ^ ((col & 7) << 4))) = vb;
    }
    __syncthreads();
    for (int ks = 0; ks < 4; ++ks) {
        s16x8 a[2], b[3];
        for (int m = 0; m < 2; ++m) {
            int r = wv * 32 + m * 16 + lr;
            a[m] = *(const s16x8*)(Ab + r * 256 + ((ks * 64 + lk * 16) ^ ((r & 7) << 4)));
        }
        for (int n = 0; n < 3; ++n) {
            int c = n * 16 + lr;
            b[n] = *(const s16x8*)(Bb + c * 256 + ((ks * 64 + lk * 16) ^ ((c & 7) << 4)));
        }
        for (int m = 0; m < 2; ++m)
            for (int n = 0; n < 3; ++n)
                acc[m][n] = __builtin_amdgcn_mfma_f32_16x16x32_bf16(a[m], b[n], acc[m][n], 0, 0, 0);
    }
    for (int m = 0; m < 2; ++m)
        for (int n = 0; n < 3; ++n)
            for (int r = 0; r < 4; ++r) {
                long row = rb + wv * 32 + m * 16 + lk * 4 + r;
                int col = n * 16 + lr;
                if (row < NN && col < 40) h2[row * 40 + col] = f2bf(acc[m][n][r]);
            }
}

__global__ void k_alpha2(const u16* __restrict__ h2, const float* __restrict__ asw,
                         const float* __restrict__ adw, float* __restrict__ as2,
                         float* __restrict__ ad2) {
    int n = blockIdx.x * blockDim.x + threadIdx.x;
    if (n >= NN) return;
    const u16* hp = h2 + (long)n * 40;
    float s = 0.f, d = 0.f;
    for (int c = 0; c < 40; c += 4) {
        u16x4 v = *(const u16x4*)(hp + c);
        for (int j = 0; j < 4; ++j) {
            float f = bf2f(v[j]);
            s += f * asw[c + j];
            d += f * adw[c + j];
        }
    }
    as2[n] = s; ad2[n] = d;
}

// ---- fused layer-2: attention + aggregate + bias + log_softmax (no max-shift)
// one wave per dst node; lanes 0..39 own one channel each. 4-wide unroll.
__global__ __launch_bounds__(256) void k_agg2(const int* __restrict__ rowptr,
                                              const int* __restrict__ csr_src,
                                              const float* __restrict__ as2,
                                              const float* __restrict__ ad2,
                                              const u16* __restrict__ h2,
                                              const float* __restrict__ b2,
                                              float* __restrict__ out) {
    int wv = threadIdx.x >> 6, lane = threadIdx.x & 63;
    long n = (long)blockIdx.x * 4 + wv;
    if (n >= NN) return;
    bool act = lane < 40;
    int cl = act ? lane : 0;                // inert lanes read ch 0 (harmless)
    float adv = ad2[n];
    int e0 = rowptr[n], e1 = rowptr[n + 1];
    float den = 0.f, acc = 0.f;
    int e = e0;
    for (; e + 3 < e1; e += 4) {
        int s0 = csr_src[e], s1 = csr_src[e + 1], s2 = csr_src[e + 2], s3 = csr_src[e + 3];
        float p0 = __expf(lrelu(as2[s0] + adv));
        float p1 = __expf(lrelu(as2[s1] + adv));
        float p2 = __expf(lrelu(as2[s2] + adv));
        float p3 = __expf(lrelu(as2[s3] + adv));
        float h0 = bf2f(h2[(long)s0 * 40 + cl]);
        float h1 = bf2f(h2[(long)s1 * 40 + cl]);
        float h2v = bf2f(h2[(long)s2 * 40 + cl]);
        float h3 = bf2f(h2[(long)s3 * 40 + cl]);
        den += (p0 + p1) + (p2 + p3);
        acc += p0 * h0 + p1 * h1 + p2 * h2v + p3 * h3;
    }
    for (; e < e1; ++e) {
        int s0 = csr_src[e];
        float p0 = __expf(lrelu(as2[s0] + adv));
        float h0 = bf2f(h2[(long)s0 * 40 + cl]);
        den += p0;
        acc += p0 * h0;
    }
    float z = acc / (den + 1e-16f) + (act ? b2[lane] : 0.f);
    float mv = act ? z : -__builtin_inff();
    for (int s = 1; s < 64; s <<= 1) mv = fmaxf(mv, __shfl_xor(mv, s, 64));
    float ex = act ? __expf(z - mv) : 0.f;
    for (int s = 1; s < 64; s <<= 1) ex += __shfl_xor(ex, s, 64);
    if (act) {
        out[n * 40 + lane] = z;
        out[ZO + n * 40 + lane] = z - mv - logf(ex);
    }
}

extern "C" void kernel_launch(void* const* d_in, const int* in_sizes, int n_in,
                              void* d_out, int out_size, void* d_ws, size_t ws_size,
                              hipStream_t stream) {
    const float* x   = (const float*)d_in[0];
    const int*   ei  = (const int*)d_in[1];
    const float* W1  = (const float*)d_in[2];
    const float* aS1 = (const float*)d_in[3];
    const float* aD1 = (const float*)d_in[4];
    const float* b1  = (const float*)d_in[5];
    const float* W2  = (const float*)d_in[6];
    const float* aS2 = (const float*)d_in[7];
    const float* aD2 = (const float*)d_in[8];
    const float* b2  = (const float*)d_in[9];
    float* out = (float*)d_out;

    // workspace layout (~73 MB, no aliasing)
    char* p = (char*)d_ws;
    u16*   h1raw   = (u16*)p;                       // 25,624,576 B (NP*128*2)
    u16*   h1b     = (u16*)(p + 25624576);          // 25,624,576 B
    int*   csr_src = (int*)(p + 51249152);          // 6,800,000 B
    u16*   h2      = (u16*)(p + 58049152);          // 8,000,000 B
    u16*   w1t     = (u16*)(p + 66049152);          // 65,536 B
    u16*   w2t     = (u16*)(p + 66114688);          // 12,288 B
    float* as1     = (float*)(p + 66126976);        // 1,600,000 B
    float* ad1     = (float*)(p + 67726976);        // 1,600,000 B
    float* as2     = (float*)(p + 69326976);        // 400,000 B
    float* ad2     = (float*)(p + 69726976);        // 400,000 B
    int*   deg     = (int*)(p + 70126976);          // 400,000 B
    int*   incl    = (int*)(p + 70526976);          // 400,000 B
    int*   rowptr  = (int*)(p + 70926976);          // 400,004 B (NN+1)
    int*   cursor  = (int*)(p + 71327744);          // 400,000 B
    int*   bsum    = (int*)(p + 71727744);          // 512 B
    int*   boff    = (int*)(p + 71728256);          // 512 B

    k_setup   <<<391, 256, 0, stream>>>(W1, W2, w1t, w2t, deg);
    k_gemm1   <<<782, 256, 0, stream>>>(x, w1t, h1raw);
    k_alpha1  <<<1563, 256, 0, stream>>>(h1raw, aS1, aD1, as1, ad1);

    // CSR build
    k_deg     <<<6641, 256, 0, stream>>>(ei, deg);
    k_scan_blk<<<NB_SCAN, 256, 0, stream>>>(deg, incl, bsum);
    k_scan_top<<<1, 128, 0, stream>>>(bsum, boff);
    k_scan_fin<<<391, 256, 0, stream>>>(deg, incl, boff, rowptr, cursor);
    k_scatter <<<6641, 256, 0, stream>>>(ei, cursor, csr_src);

    // layer 1 fused attention+aggregate -> bf16 h1
    k_agg1    <<<25024, 256, 0, stream>>>(rowptr, csr_src, as1, ad1, h1raw, b1, h1b);

    // layer 2
    k_gemm2   <<<782, 256, 0, stream>>>(h1b, w2t, h2);
    k_alpha2  <<<391, 256, 0, stream>>>(h2, aS2, aD2, as2, ad2);
    k_agg2    <<<25000, 256, 0, stream>>>(rowptr, csr_src, as2, ad2, h2, b2, out);
}